// Round 1
// baseline (1236.797 us; speedup 1.0000x reference)
//
#include <hip/hip_runtime.h>
#include <hip/hip_bf16.h>

#define N_NODES 100000
#define N_EDGES 1600000
#define IN_F 512
#define HID 128
#define OUT_F 32
#define ALPHA 0.01f
#define K_STEPS 10

// ============================ CSR build ============================

__global__ void hist_kernel(const int* __restrict__ er, int* __restrict__ cnt, int n) {
    int i = blockIdx.x * blockDim.x + threadIdx.x;
    int stride = gridDim.x * blockDim.x;
    for (; i < n; i += stride) atomicAdd(&cnt[er[i]], 1);
}

#define SCAN_B 512
__global__ void scan_block_kernel(const int* __restrict__ cnt, int* __restrict__ partial,
                                  int* __restrict__ bsum, int n) {
    __shared__ int s[SCAN_B];
    int tid = threadIdx.x;
    int i = blockIdx.x * SCAN_B + tid;
    int v = (i < n) ? cnt[i] : 0;
    s[tid] = v;
    __syncthreads();
    for (int off = 1; off < SCAN_B; off <<= 1) {
        int t = (tid >= off) ? s[tid - off] : 0;
        __syncthreads();
        s[tid] += t;
        __syncthreads();
    }
    if (i < n) partial[i] = s[tid];
    if (tid == SCAN_B - 1) bsum[blockIdx.x] = s[tid];
}

__global__ void scan_tops_kernel(int* __restrict__ bsum, int nb) {
    if (threadIdx.x == 0 && blockIdx.x == 0) {
        int run = 0;
        for (int b = 0; b < nb; ++b) { int t = bsum[b]; bsum[b] = run; run += t; }
    }
}

__global__ void scan_finish_kernel(const int* __restrict__ partial, const int* __restrict__ bsum,
                                   const int* __restrict__ cnt, int* __restrict__ rowptr,
                                   int* __restrict__ cursor, int n) {
    int i = blockIdx.x * blockDim.x + threadIdx.x;
    if (i < n) {
        int inc = partial[i] + bsum[i / SCAN_B];
        int exc = inc - cnt[i];
        rowptr[i] = exc;
        cursor[i] = exc;
        if (i == n - 1) rowptr[n] = inc;
    }
}

__global__ void fill_kernel(const int* __restrict__ er, const int* __restrict__ ec,
                            const float* __restrict__ ev, int* __restrict__ cursor,
                            int* __restrict__ ci, float* __restrict__ cv, int n) {
    int i = blockIdx.x * blockDim.x + threadIdx.x;
    int stride = gridDim.x * blockDim.x;
    for (; i < n; i += stride) {
        int r = er[i];
        int pos = atomicAdd(&cursor[r], 1);
        ci[pos] = ec[i];
        cv[pos] = ev[i];
    }
}

// ============================ GEMM1: x @ W1 + b1, relu ============================
// M=100000, K=512, N=128. Tile 128x128, BK=16, 8x8 micro-tile per thread, 256 threads.

__launch_bounds__(256)
__global__ void gemm1_kernel(const float* __restrict__ X, const float* __restrict__ W,
                             const float* __restrict__ bias, float* __restrict__ H, int M) {
    __shared__ float xs[16][132];   // transposed x tile: xs[k][m], padded
    __shared__ float ws[16][132];   // w tile: ws[k][n], padded
    const int tid = threadIdx.x;
    const int m0 = blockIdx.x * 128;
    const int tx = tid & 15, ty = tid >> 4;

    float acc[8][8];
    #pragma unroll
    for (int i = 0; i < 8; ++i)
        #pragma unroll
        for (int j = 0; j < 8; ++j) acc[i][j] = 0.f;

    for (int k0 = 0; k0 < IN_F; k0 += 16) {
        #pragma unroll
        for (int s = 0; s < 2; ++s) {
            int c = tid + s * 256;            // 0..511
            // stage X tile (transpose into xs[k][m])
            int m = c >> 2, kq = c & 3;
            int gm = m0 + m; if (gm >= M) gm = M - 1;
            float4 v = *reinterpret_cast<const float4*>(X + (size_t)gm * IN_F + k0 + kq * 4);
            xs[kq * 4 + 0][m] = v.x;
            xs[kq * 4 + 1][m] = v.y;
            xs[kq * 4 + 2][m] = v.z;
            xs[kq * 4 + 3][m] = v.w;
            // stage W tile
            int k = c >> 5, nq = c & 31;
            float4 w = *reinterpret_cast<const float4*>(W + (size_t)(k0 + k) * HID + nq * 4);
            *reinterpret_cast<float4*>(&ws[k][nq * 4]) = w;
        }
        __syncthreads();
        #pragma unroll
        for (int kk = 0; kk < 16; ++kk) {
            float4 a0 = *reinterpret_cast<const float4*>(&xs[kk][ty * 8]);
            float4 a1 = *reinterpret_cast<const float4*>(&xs[kk][ty * 8 + 4]);
            float4 b0 = *reinterpret_cast<const float4*>(&ws[kk][tx * 8]);
            float4 b1 = *reinterpret_cast<const float4*>(&ws[kk][tx * 8 + 4]);
            float a[8] = {a0.x, a0.y, a0.z, a0.w, a1.x, a1.y, a1.z, a1.w};
            float b[8] = {b0.x, b0.y, b0.z, b0.w, b1.x, b1.y, b1.z, b1.w};
            #pragma unroll
            for (int i = 0; i < 8; ++i)
                #pragma unroll
                for (int j = 0; j < 8; ++j) acc[i][j] = fmaf(a[i], b[j], acc[i][j]);
        }
        __syncthreads();
    }
    // epilogue: bias + relu, float4 stores
    float bb[8];
    #pragma unroll
    for (int j = 0; j < 8; ++j) bb[j] = bias[tx * 8 + j];
    #pragma unroll
    for (int i = 0; i < 8; ++i) {
        int gm = m0 + ty * 8 + i;
        if (gm < M) {
            float4 o0, o1;
            o0.x = fmaxf(acc[i][0] + bb[0], 0.f);
            o0.y = fmaxf(acc[i][1] + bb[1], 0.f);
            o0.z = fmaxf(acc[i][2] + bb[2], 0.f);
            o0.w = fmaxf(acc[i][3] + bb[3], 0.f);
            o1.x = fmaxf(acc[i][4] + bb[4], 0.f);
            o1.y = fmaxf(acc[i][5] + bb[5], 0.f);
            o1.z = fmaxf(acc[i][6] + bb[6], 0.f);
            o1.w = fmaxf(acc[i][7] + bb[7], 0.f);
            *reinterpret_cast<float4*>(H + (size_t)gm * HID + tx * 8) = o0;
            *reinterpret_cast<float4*>(H + (size_t)gm * HID + tx * 8 + 4) = o1;
        }
    }
}

// ============================ GEMM2: h1 @ W2 + b2, relu ============================
// One thread per (row, col): 32 cols, 8 rows per 256-thread block. W2 in LDS.

__launch_bounds__(256)
__global__ void gemm2_kernel(const float* __restrict__ H1, const float* __restrict__ W2,
                             const float* __restrict__ bias, float* __restrict__ H, int M) {
    __shared__ float w2s[HID * OUT_F];
    int tid = threadIdx.x;
    for (int idx = tid; idx < HID * OUT_F; idx += 256) w2s[idx] = W2[idx];
    __syncthreads();
    int col = tid & 31;
    int r = blockIdx.x * 8 + (tid >> 5);
    if (r >= M) return;
    const float* hrow = H1 + (size_t)r * HID;
    float acc = bias[col];
    #pragma unroll 8
    for (int k = 0; k < HID; k += 4) {
        float4 hv = *reinterpret_cast<const float4*>(hrow + k);
        acc = fmaf(hv.x, w2s[(k + 0) * OUT_F + col], acc);
        acc = fmaf(hv.y, w2s[(k + 1) * OUT_F + col], acc);
        acc = fmaf(hv.z, w2s[(k + 2) * OUT_F + col], acc);
        acc = fmaf(hv.w, w2s[(k + 3) * OUT_F + col], acc);
    }
    H[(size_t)r * OUT_F + col] = fmaxf(acc, 0.f);
}

// ============================ SpMM step ============================
// dst[r][j] = 0.99 * sum_{e in row r} val_e * src[col_e][j] + 0.01 * src[r][j]
// 32 lanes per row (lane = feature), 8 rows per 256-thread block.

__launch_bounds__(256)
__global__ void spmm_kernel(const int* __restrict__ rowptr, const int* __restrict__ ci,
                            const float* __restrict__ cv, const float* __restrict__ src,
                            float* __restrict__ dst, int n) {
    int lane = threadIdx.x & 31;
    int r = blockIdx.x * 8 + (threadIdx.x >> 5);
    if (r >= n) return;
    int s = rowptr[r], e = rowptr[r + 1];
    float acc = 0.f;
    int i = s;
    for (; i + 2 <= e; i += 2) {
        int c0 = ci[i], c1 = ci[i + 1];
        float v0 = cv[i], v1 = cv[i + 1];
        acc = fmaf(v0, src[(size_t)c0 * OUT_F + lane], acc);
        acc = fmaf(v1, src[(size_t)c1 * OUT_F + lane], acc);
    }
    if (i < e) acc = fmaf(cv[i], src[(size_t)ci[i] * OUT_F + lane], acc);
    float self = src[(size_t)r * OUT_F + lane];
    dst[(size_t)r * OUT_F + lane] = (1.f - ALPHA) * acc + ALPHA * self;
}

// ============================ launch ============================

extern "C" void kernel_launch(void* const* d_in, const int* in_sizes, int n_in,
                              void* d_out, int out_size, void* d_ws, size_t ws_size,
                              hipStream_t stream) {
    const float* x  = (const float*)d_in[0];
    const int*   er = (const int*)d_in[1];
    const int*   ec = (const int*)d_in[2];
    const float* ev = (const float*)d_in[3];
    const float* W1 = (const float*)d_in[4];
    const float* b1 = (const float*)d_in[5];
    const float* W2 = (const float*)d_in[6];
    const float* b2 = (const float*)d_in[7];
    float* out = (float*)d_out;

    char* ws = (char*)d_ws;
    float* h1     = (float*)(ws + 0);          // 100000*128*4 = 51,200,000
    float* bufA   = (float*)(ws + 51200000);   // 12,800,000
    float* bufB   = (float*)(ws + 64000000);   // 12,800,000
    int*   rowptr = (int*)  (ws + 76800000);   // (N+1)*4 -> pad to 400,016
    int*   cnt    = (int*)  (ws + 77200016);   // 400,000
    int*   cursor = (int*)  (ws + 77600016);   // 400,000
    int*   partial= (int*)  (ws + 78000016);   // 400,000
    int*   bsum   = (int*)  (ws + 78400016);   // 1,024
    int*   ci     = (int*)  (ws + 78401040);   // 6,400,000
    float* cv     = (float*)(ws + 84801040);   // 6,400,000  (total ~91.2 MB)

    // ---- CSR build ----
    hipMemsetAsync(cnt, 0, N_NODES * sizeof(int), stream);
    hist_kernel<<<2048, 256, 0, stream>>>(er, cnt, N_EDGES);
    int nb = (N_NODES + SCAN_B - 1) / SCAN_B;  // 196
    scan_block_kernel<<<nb, SCAN_B, 0, stream>>>(cnt, partial, bsum, N_NODES);
    scan_tops_kernel<<<1, 64, 0, stream>>>(bsum, nb);
    scan_finish_kernel<<<(N_NODES + 255) / 256, 256, 0, stream>>>(partial, bsum, cnt, rowptr,
                                                                  cursor, N_NODES);
    fill_kernel<<<2048, 256, 0, stream>>>(er, ec, ev, cursor, ci, cv, N_EDGES);

    // ---- MLP ----
    gemm1_kernel<<<(N_NODES + 127) / 128, 256, 0, stream>>>(x, W1, b1, h1, N_NODES);
    gemm2_kernel<<<(N_NODES + 7) / 8, 256, 0, stream>>>(h1, W2, b2, bufA, N_NODES);

    // ---- propagation ----
    float* src = bufA;
    for (int step = 0; step < K_STEPS; ++step) {
        float* dst = (step == K_STEPS - 1) ? out : ((step & 1) ? bufA : bufB);
        spmm_kernel<<<(N_NODES + 7) / 8, 256, 0, stream>>>(rowptr, ci, cv, src, dst, N_NODES);
        src = dst;
    }
}

// Round 2
// 837.259 us; speedup vs baseline: 1.4772x; 1.4772x over previous
//
#include <hip/hip_runtime.h>
#include <hip/hip_bf16.h>

#define N_NODES 100000
#define N_EDGES 1600000
#define IN_F 512
#define HID 128
#define OUT_F 32
#define ALPHA 0.01f
#define K_STEPS 10

typedef __attribute__((ext_vector_type(8))) short short8;
typedef __attribute__((ext_vector_type(4))) float f32x4;

__device__ __forceinline__ unsigned short f2bf(float f) {
    union { float f; unsigned u; } c; c.f = f;
    unsigned r = c.u + 0x7FFF + ((c.u >> 16) & 1);   // RNE
    return (unsigned short)(r >> 16);
}

// ============================ CSR build ============================

__global__ void hist_kernel(const int* __restrict__ er, int* __restrict__ cnt, int n) {
    int i = blockIdx.x * blockDim.x + threadIdx.x;
    int stride = gridDim.x * blockDim.x;
    for (; i < n; i += stride) atomicAdd(&cnt[er[i]], 1);
}

#define SCAN_B 512
__global__ void scan_block_kernel(const int* __restrict__ cnt, int* __restrict__ partial,
                                  int* __restrict__ bsum, int n) {
    __shared__ int s[SCAN_B];
    int tid = threadIdx.x;
    int i = blockIdx.x * SCAN_B + tid;
    int v = (i < n) ? cnt[i] : 0;
    s[tid] = v;
    __syncthreads();
    for (int off = 1; off < SCAN_B; off <<= 1) {
        int t = (tid >= off) ? s[tid - off] : 0;
        __syncthreads();
        s[tid] += t;
        __syncthreads();
    }
    if (i < n) partial[i] = s[tid];
    if (tid == SCAN_B - 1) bsum[blockIdx.x] = s[tid];
}

// parallel exclusive scan of <=256 block sums, one block
__global__ void scan_tops_kernel(int* __restrict__ bsum, int nb) {
    __shared__ int s[256];
    int t = threadIdx.x;
    int v = (t < nb) ? bsum[t] : 0;
    s[t] = v;
    __syncthreads();
    for (int off = 1; off < 256; off <<= 1) {
        int x = (t >= off) ? s[t - off] : 0;
        __syncthreads();
        s[t] += x;
        __syncthreads();
    }
    if (t < nb) bsum[t] = s[t] - v;   // exclusive
}

__global__ void scan_finish_kernel(const int* __restrict__ partial, const int* __restrict__ bsum,
                                   const int* __restrict__ cnt, int* __restrict__ rowptr,
                                   int* __restrict__ cursor, int n) {
    int i = blockIdx.x * blockDim.x + threadIdx.x;
    if (i < n) {
        int inc = partial[i] + bsum[i / SCAN_B];
        int exc = inc - cnt[i];
        rowptr[i] = exc;
        cursor[i] = exc;
        if (i == n - 1) rowptr[n] = inc;
    }
}

__global__ void fill_kernel(const int* __restrict__ er, const int* __restrict__ ec,
                            const float* __restrict__ ev, int* __restrict__ cursor,
                            int2* __restrict__ edges, int n) {
    int i = blockIdx.x * blockDim.x + threadIdx.x;
    int stride = gridDim.x * blockDim.x;
    for (; i < n; i += stride) {
        int r = er[i];
        int pos = atomicAdd(&cursor[r], 1);
        edges[pos] = make_int2(ec[i], __float_as_int(ev[i]));
    }
}

// ============================ weight pre-convert ============================
// W1 [512][128] f32 -> W1T [128][512] bf16 ; W2 [128][32] f32 -> W2T [32][128] bf16

__global__ void wconv_kernel(const float* __restrict__ W1, const float* __restrict__ W2,
                             short* __restrict__ W1T, short* __restrict__ W2T) {
    int idx = blockIdx.x * 256 + threadIdx.x;
    if (idx < IN_F * HID) {
        int k = idx >> 7, nn = idx & 127;
        W1T[nn * IN_F + k] = (short)f2bf(W1[idx]);
    }
    if (idx < HID * OUT_F) {
        int k = idx >> 5, nn = idx & 31;
        W2T[nn * HID + k] = (short)f2bf(W2[idx]);
    }
}

// ============================ fused MLP ============================
// H2 = relu(relu(X@W1 + b1) @ W2 + b2), bf16 MFMA, 128-row tile per block, 4 waves.
// LDS: As [128][40] bf16, Bs [128][40] bf16 (k-chunk 32, pad +8)
//      reused as H1s [128][136] bf16; W2s [32][136] bf16 separate.

#define AB_PITCH 40
#define H1_PITCH 136

__launch_bounds__(256)
__global__ void mlp_kernel(const float* __restrict__ X, const short* __restrict__ W1T,
                           const float* __restrict__ b1, const short* __restrict__ W2T,
                           const float* __restrict__ b2, float* __restrict__ H, int M) {
    __shared__ char lds[43520];
    short* As  = (short*)lds;              // 128*40*2 = 10240
    short* Bs  = (short*)(lds + 10240);    // 10240
    short* H1s = (short*)lds;              // 128*136*2 = 34816 (reuses As/Bs after K loop)
    short* W2s = (short*)(lds + 34816);    // 32*136*2 = 8704

    const int t = threadIdx.x;
    const int m0 = blockIdx.x * 128;
    const int l = t & 63;
    const int w = t >> 6;                  // wave 0..3 -> rows [32w, 32w+32)
    const int l15 = l & 15;
    const int koff = (l >> 4) << 3;        // 0,8,16,24

    // stage W2T -> W2s (once); visible after first barrier in K loop
    {
        int nn = t >> 3, seg = (t & 7) << 4;          // 32 rows x 8 segs of 16
        const short8* src = (const short8*)(W2T + nn * HID + seg);
        *(short8*)&W2s[nn * H1_PITCH + seg] = src[0];
        *(short8*)&W2s[nn * H1_PITCH + seg + 8] = src[1];
    }

    const int arow = t >> 1;               // 0..127
    const int ah = (t & 1) << 4;           // 0 or 16
    int gm = m0 + arow; if (gm >= M) gm = M - 1;
    const float* xrow = X + (size_t)gm * IN_F;
    const short* wrow = W1T + (size_t)arow * IN_F;

    f32x4 acc[2][8];
    #pragma unroll
    for (int m = 0; m < 2; ++m)
        #pragma unroll
        for (int n = 0; n < 8; ++n) acc[m][n] = (f32x4){0.f, 0.f, 0.f, 0.f};

    for (int k0 = 0; k0 < IN_F; k0 += 32) {
        // ---- stage A (fp32 -> bf16) ----
        float4 v0 = *(const float4*)(xrow + k0 + ah);
        float4 v1 = *(const float4*)(xrow + k0 + ah + 4);
        float4 v2 = *(const float4*)(xrow + k0 + ah + 8);
        float4 v3 = *(const float4*)(xrow + k0 + ah + 12);
        short8 p0, p1;
        p0[0] = f2bf(v0.x); p0[1] = f2bf(v0.y); p0[2] = f2bf(v0.z); p0[3] = f2bf(v0.w);
        p0[4] = f2bf(v1.x); p0[5] = f2bf(v1.y); p0[6] = f2bf(v1.z); p0[7] = f2bf(v1.w);
        p1[0] = f2bf(v2.x); p1[1] = f2bf(v2.y); p1[2] = f2bf(v2.z); p1[3] = f2bf(v2.w);
        p1[4] = f2bf(v3.x); p1[5] = f2bf(v3.y); p1[6] = f2bf(v3.z); p1[7] = f2bf(v3.w);
        // ---- stage B (bf16 copy) ----
        short8 q0 = *(const short8*)(wrow + k0 + ah);
        short8 q1 = *(const short8*)(wrow + k0 + ah + 8);
        __syncthreads();   // previous iter's reads done before overwrite
        *(short8*)&As[arow * AB_PITCH + ah] = p0;
        *(short8*)&As[arow * AB_PITCH + ah + 8] = p1;
        *(short8*)&Bs[arow * AB_PITCH + ah] = q0;
        *(short8*)&Bs[arow * AB_PITCH + ah + 8] = q1;
        __syncthreads();
        // ---- MFMA ----
        short8 af0 = *(const short8*)&As[(32 * w + l15) * AB_PITCH + koff];
        short8 af1 = *(const short8*)&As[(32 * w + 16 + l15) * AB_PITCH + koff];
        #pragma unroll
        for (int n = 0; n < 8; ++n) {
            short8 bf = *(const short8*)&Bs[(16 * n + l15) * AB_PITCH + koff];
            acc[0][n] = __builtin_amdgcn_mfma_f32_16x16x32_bf16(af0, bf, acc[0][n], 0, 0, 0);
            acc[1][n] = __builtin_amdgcn_mfma_f32_16x16x32_bf16(af1, bf, acc[1][n], 0, 0, 0);
        }
    }

    // ---- bias1 + relu -> H1s (bf16) ----
    float bcol[8];
    #pragma unroll
    for (int n = 0; n < 8; ++n) bcol[n] = b1[16 * n + l15];
    __syncthreads();   // all MFMA LDS reads done before H1s overwrites As/Bs
    #pragma unroll
    for (int m = 0; m < 2; ++m)
        #pragma unroll
        for (int n = 0; n < 8; ++n)
            #pragma unroll
            for (int reg = 0; reg < 4; ++reg) {
                int hrow = 32 * w + 16 * m + ((l >> 4) << 2) + reg;
                float v = fmaxf(acc[m][n][reg] + bcol[n], 0.f);
                H1s[hrow * H1_PITCH + 16 * n + l15] = (short)f2bf(v);
            }
    __syncthreads();

    // ---- GEMM2: H1s[128][128] @ W2s -> 128x32 ----
    f32x4 acc2[2][2];
    #pragma unroll
    for (int m = 0; m < 2; ++m)
        #pragma unroll
        for (int n = 0; n < 2; ++n) acc2[m][n] = (f32x4){0.f, 0.f, 0.f, 0.f};
    #pragma unroll
    for (int kc = 0; kc < 4; ++kc) {
        short8 a0 = *(const short8*)&H1s[(32 * w + l15) * H1_PITCH + (kc << 5) + koff];
        short8 a1 = *(const short8*)&H1s[(32 * w + 16 + l15) * H1_PITCH + (kc << 5) + koff];
        #pragma unroll
        for (int n = 0; n < 2; ++n) {
            short8 bf = *(const short8*)&W2s[(16 * n + l15) * H1_PITCH + (kc << 5) + koff];
            acc2[0][n] = __builtin_amdgcn_mfma_f32_16x16x32_bf16(a0, bf, acc2[0][n], 0, 0, 0);
            acc2[1][n] = __builtin_amdgcn_mfma_f32_16x16x32_bf16(a1, bf, acc2[1][n], 0, 0, 0);
        }
    }
    // ---- bias2 + relu -> global ----
    #pragma unroll
    for (int n = 0; n < 2; ++n) {
        float bc = b2[16 * n + l15];
        #pragma unroll
        for (int m = 0; m < 2; ++m)
            #pragma unroll
            for (int reg = 0; reg < 4; ++reg) {
                int row = 32 * w + 16 * m + ((l >> 4) << 2) + reg;
                int g = m0 + row;
                if (g < M) H[(size_t)g * OUT_F + 16 * n + l15] = fmaxf(acc2[m][n][reg] + bc, 0.f);
            }
    }
}

// ============================ SpMM step ============================
// dst[r][:] = 0.99 * sum val_e * src[col_e][:] + 0.01 * src[r][:]
// 8 lanes per row, float4 per lane, int2-packed edges, unroll 4.

__launch_bounds__(256)
__global__ void spmm_kernel(const int* __restrict__ rowptr, const int2* __restrict__ edges,
                            const float4* __restrict__ src, float4* __restrict__ dst, int n) {
    int g = blockIdx.x * 256 + threadIdx.x;
    int r = g >> 3, lane = g & 7;
    if (r >= n) return;
    int s = rowptr[r], e = rowptr[r + 1];
    float ax = 0.f, ay = 0.f, az = 0.f, aw = 0.f;
    int i = s;
    for (; i + 4 <= e; i += 4) {
        int2 e0 = edges[i], e1 = edges[i + 1], e2 = edges[i + 2], e3 = edges[i + 3];
        float4 v0 = src[(size_t)e0.x * 8 + lane];
        float4 v1 = src[(size_t)e1.x * 8 + lane];
        float4 v2 = src[(size_t)e2.x * 8 + lane];
        float4 v3 = src[(size_t)e3.x * 8 + lane];
        float w0 = __int_as_float(e0.y), w1 = __int_as_float(e1.y);
        float w2 = __int_as_float(e2.y), w3 = __int_as_float(e3.y);
        ax = fmaf(w0, v0.x, ax); ay = fmaf(w0, v0.y, ay); az = fmaf(w0, v0.z, az); aw = fmaf(w0, v0.w, aw);
        ax = fmaf(w1, v1.x, ax); ay = fmaf(w1, v1.y, ay); az = fmaf(w1, v1.z, az); aw = fmaf(w1, v1.w, aw);
        ax = fmaf(w2, v2.x, ax); ay = fmaf(w2, v2.y, ay); az = fmaf(w2, v2.z, az); aw = fmaf(w2, v2.w, aw);
        ax = fmaf(w3, v3.x, ax); ay = fmaf(w3, v3.y, ay); az = fmaf(w3, v3.z, az); aw = fmaf(w3, v3.w, aw);
    }
    for (; i < e; ++i) {
        int2 e0 = edges[i];
        float4 v0 = src[(size_t)e0.x * 8 + lane];
        float w0 = __int_as_float(e0.y);
        ax = fmaf(w0, v0.x, ax); ay = fmaf(w0, v0.y, ay); az = fmaf(w0, v0.z, az); aw = fmaf(w0, v0.w, aw);
    }
    float4 self = src[(size_t)r * 8 + lane];
    float4 o;
    o.x = (1.f - ALPHA) * ax + ALPHA * self.x;
    o.y = (1.f - ALPHA) * ay + ALPHA * self.y;
    o.z = (1.f - ALPHA) * az + ALPHA * self.z;
    o.w = (1.f - ALPHA) * aw + ALPHA * self.w;
    dst[(size_t)r * 8 + lane] = o;
}

// ============================ launch ============================

extern "C" void kernel_launch(void* const* d_in, const int* in_sizes, int n_in,
                              void* d_out, int out_size, void* d_ws, size_t ws_size,
                              hipStream_t stream) {
    const float* x  = (const float*)d_in[0];
    const int*   er = (const int*)d_in[1];
    const int*   ec = (const int*)d_in[2];
    const float* ev = (const float*)d_in[3];
    const float* W1 = (const float*)d_in[4];
    const float* b1 = (const float*)d_in[5];
    const float* W2 = (const float*)d_in[6];
    const float* b2 = (const float*)d_in[7];
    float* out = (float*)d_out;

    char* ws = (char*)d_ws;
    float* bufA   = (float*)(ws + 0);           // 12,800,000
    float* bufB   = (float*)(ws + 12800000);    // 12,800,000
    int2*  edges  = (int2*) (ws + 25600000);    // 12,800,000
    short* W1T    = (short*)(ws + 38400000);    // 131,072
    short* W2T    = (short*)(ws + 38531072);    // 8,192
    int*   rowptr = (int*)  (ws + 38539264);    // 400,016
    int*   cnt    = (int*)  (ws + 38939280);    // 400,000
    int*   cursor = (int*)  (ws + 39339280);    // 400,000
    int*   partial= (int*)  (ws + 39739280);    // 400,000
    int*   bsum   = (int*)  (ws + 40139280);    // 1,024

    // ---- CSR build ----
    hipMemsetAsync(cnt, 0, N_NODES * sizeof(int), stream);
    hist_kernel<<<2048, 256, 0, stream>>>(er, cnt, N_EDGES);
    int nb = (N_NODES + SCAN_B - 1) / SCAN_B;  // 196
    scan_block_kernel<<<nb, SCAN_B, 0, stream>>>(cnt, partial, bsum, N_NODES);
    scan_tops_kernel<<<1, 256, 0, stream>>>(bsum, nb);
    scan_finish_kernel<<<(N_NODES + 255) / 256, 256, 0, stream>>>(partial, bsum, cnt, rowptr,
                                                                  cursor, N_NODES);
    fill_kernel<<<2048, 256, 0, stream>>>(er, ec, ev, cursor, edges, N_EDGES);

    // ---- weights to bf16 (transposed) ----
    wconv_kernel<<<(IN_F * HID + 255) / 256, 256, 0, stream>>>(W1, W2, W1T, W2T);

    // ---- fused MLP ----
    mlp_kernel<<<(N_NODES + 127) / 128, 256, 0, stream>>>(x, W1T, b1, W2T, b2, bufA, N_NODES);

    // ---- propagation ----
    float* src = bufA;
    for (int step = 0; step < K_STEPS; ++step) {
        float* dst = (step == K_STEPS - 1) ? out : ((step & 1) ? bufA : bufB);
        spmm_kernel<<<(N_NODES * 8 + 255) / 256, 256, 0, stream>>>(
            rowptr, edges, (const float4*)src, (float4*)dst, N_NODES);
        src = dst;
    }
}

// Round 3
// 651.038 us; speedup vs baseline: 1.8997x; 1.2860x over previous
//
#include <hip/hip_runtime.h>
#include <hip/hip_bf16.h>

#define N_NODES 100000
#define N_EDGES 1600000
#define IN_F 512
#define HID 128
#define OUT_F 32
#define ALPHA 0.01f
#define K_STEPS 10

// bucketed CSR build params
#define NB 256          // phase-1 blocks
#define CH 6250         // edges per phase-1 block (NB*CH == N_EDGES exactly)
#define NBUCK 391       // buckets of 256 rows: ceil(100000/256)
#define NS (NBUCK * NB) // scan size = 100096
#define CAP 5120        // LDS stage capacity per bucket (mean 4096, sigma 64)

typedef __attribute__((ext_vector_type(8))) short short8;
typedef __attribute__((ext_vector_type(4))) float f32x4;
typedef __attribute__((ext_vector_type(8))) _Float16 half8;

__device__ __forceinline__ unsigned short f2bf(float f) {
    union { float f; unsigned u; } c; c.f = f;
    unsigned r = c.u + 0x7FFF + ((c.u >> 16) & 1);   // RNE
    return (unsigned short)(r >> 16);
}

// ============================ CSR build: phase 1 (bucket histogram) ============================

__launch_bounds__(256)
__global__ void p1_hist_kernel(const int* __restrict__ er, int* __restrict__ S) {
    __shared__ int h[NBUCK];
    int t = threadIdx.x, bl = blockIdx.x;
    for (int b = t; b < NBUCK; b += 256) h[b] = 0;
    __syncthreads();
    int s = bl * CH, e = s + CH;
    for (int i = s + t; i < e; i += 256) atomicAdd(&h[er[i] >> 8], 1);
    __syncthreads();
    for (int b = t; b < NBUCK; b += 256) S[b * NB + bl] = h[b];
}

// ============================ generic exclusive scan (3 kernels) ============================

#define SCAN_B 512
__global__ void scan_block_kernel(const int* __restrict__ cnt, int* __restrict__ partial,
                                  int* __restrict__ bsum, int n) {
    __shared__ int s[SCAN_B];
    int tid = threadIdx.x;
    int i = blockIdx.x * SCAN_B + tid;
    int v = (i < n) ? cnt[i] : 0;
    s[tid] = v;
    __syncthreads();
    for (int off = 1; off < SCAN_B; off <<= 1) {
        int t = (tid >= off) ? s[tid - off] : 0;
        __syncthreads();
        s[tid] += t;
        __syncthreads();
    }
    if (i < n) partial[i] = s[tid];
    if (tid == SCAN_B - 1) bsum[blockIdx.x] = s[tid];
}

__global__ void scan_tops_kernel(int* __restrict__ bsum, int nb) {
    __shared__ int s[256];
    int t = threadIdx.x;
    int v = (t < nb) ? bsum[t] : 0;
    s[t] = v;
    __syncthreads();
    for (int off = 1; off < 256; off <<= 1) {
        int x = (t >= off) ? s[t - off] : 0;
        __syncthreads();
        s[t] += x;
        __syncthreads();
    }
    if (t < nb) bsum[t] = s[t] - v;   // exclusive
}

__global__ void scan_finish_excl_kernel(const int* __restrict__ partial, const int* __restrict__ bsum,
                                        const int* __restrict__ cnt, int* __restrict__ excl, int n) {
    int i = blockIdx.x * blockDim.x + threadIdx.x;
    if (i < n) excl[i] = partial[i] + bsum[i / SCAN_B] - cnt[i];
}

// ============================ CSR build: phase 1 scatter (by bucket) ============================
// sorted[pos] = { col | (localrow<<17), val }

__launch_bounds__(256)
__global__ void p1_scatter_kernel(const int* __restrict__ er, const int* __restrict__ ec,
                                  const float* __restrict__ ev, const int* __restrict__ Sexcl,
                                  int2* __restrict__ sorted) {
    __shared__ int cur[NBUCK];
    int t = threadIdx.x, bl = blockIdx.x;
    for (int b = t; b < NBUCK; b += 256) cur[b] = Sexcl[b * NB + bl];
    __syncthreads();
    int s = bl * CH, e = s + CH;
    for (int i = s + t; i < e; i += 256) {
        int r = er[i];
        int b = r >> 8;
        int pos = atomicAdd(&cur[b], 1);
        sorted[pos] = make_int2(ec[i] | ((r & 255) << 17), __float_as_int(ev[i]));
    }
}

// ============================ CSR build: phase 2 (sort within bucket, in LDS) ============================

__launch_bounds__(256)
__global__ void p2_build_kernel(const int2* __restrict__ sorted, const int* __restrict__ Sexcl,
                                int* __restrict__ rowptr, int2* __restrict__ edges) {
    __shared__ int rcnt[256], rexcl[256], rcur[256], sc[256];
    __shared__ int2 stage[CAP];
    int t = threadIdx.x, b = blockIdx.x;
    int base = Sexcl[b * NB];
    int end = (b == NBUCK - 1) ? N_EDGES : Sexcl[(b + 1) * NB];
    int cnt = end - base;
    rcnt[t] = 0; rcur[t] = 0;
    __syncthreads();
    for (int i = t; i < cnt; i += 256)
        atomicAdd(&rcnt[((unsigned)sorted[base + i].x) >> 17], 1);
    __syncthreads();
    // exclusive scan of rcnt
    int v = rcnt[t];
    sc[t] = v;
    __syncthreads();
    for (int off = 1; off < 256; off <<= 1) {
        int x = (t >= off) ? sc[t - off] : 0;
        __syncthreads();
        sc[t] += x;
        __syncthreads();
    }
    rexcl[t] = sc[t] - v;
    // rowptr (coalesced)
    int row = (b << 8) + t;
    if (row < N_NODES) rowptr[row] = base + sc[t] - v;
    if (b == NBUCK - 1 && t == 0) rowptr[N_NODES] = N_EDGES;
    __syncthreads();
    // place into LDS stage ordered by row
    for (int i = t; i < cnt; i += 256) {
        int2 ed = sorted[base + i];
        int lr = ((unsigned)ed.x) >> 17;
        int2 o = make_int2(ed.x & 0x1FFFF, ed.y);
        int pos = rexcl[lr] + atomicAdd(&rcur[lr], 1);
        if (pos < CAP) stage[pos] = o;
        else edges[base + pos] = o;   // overflow fallback (statistically never)
    }
    __syncthreads();
    // stream out coalesced
    int lim = cnt < CAP ? cnt : CAP;
    for (int i = t; i < lim; i += 256) edges[base + i] = stage[i];
}

// ============================ weight pre-convert ============================

__global__ void wconv_kernel(const float* __restrict__ W1, const float* __restrict__ W2,
                             short* __restrict__ W1T, short* __restrict__ W2T) {
    int idx = blockIdx.x * 256 + threadIdx.x;
    if (idx < IN_F * HID) {
        int k = idx >> 7, nn = idx & 127;
        W1T[nn * IN_F + k] = (short)f2bf(W1[idx]);
    }
    if (idx < HID * OUT_F) {
        int k = idx >> 5, nn = idx & 31;
        W2T[nn * HID + k] = (short)f2bf(W2[idx]);
    }
}

// ============================ fused MLP (bf16 MFMA), fp16 output ============================

#define AB_PITCH 40
#define H1_PITCH 136

__launch_bounds__(256)
__global__ void mlp_kernel(const float* __restrict__ X, const short* __restrict__ W1T,
                           const float* __restrict__ b1, const short* __restrict__ W2T,
                           const float* __restrict__ b2, _Float16* __restrict__ H, int M) {
    __shared__ char lds[43520];
    short* As  = (short*)lds;              // 128*40*2 = 10240
    short* Bs  = (short*)(lds + 10240);    // 10240
    short* H1s = (short*)lds;              // 128*136*2 = 34816 (reuses As/Bs)
    short* W2s = (short*)(lds + 34816);    // 32*136*2 = 8704

    const int t = threadIdx.x;
    const int m0 = blockIdx.x * 128;
    const int l = t & 63;
    const int w = t >> 6;
    const int l15 = l & 15;
    const int koff = (l >> 4) << 3;

    {
        int nn = t >> 3, seg = (t & 7) << 4;
        const short8* src = (const short8*)(W2T + nn * HID + seg);
        *(short8*)&W2s[nn * H1_PITCH + seg] = src[0];
        *(short8*)&W2s[nn * H1_PITCH + seg + 8] = src[1];
    }

    const int arow = t >> 1;
    const int ah = (t & 1) << 4;
    int gm = m0 + arow; if (gm >= M) gm = M - 1;
    const float* xrow = X + (size_t)gm * IN_F;
    const short* wrow = W1T + (size_t)arow * IN_F;

    f32x4 acc[2][8];
    #pragma unroll
    for (int m = 0; m < 2; ++m)
        #pragma unroll
        for (int n = 0; n < 8; ++n) acc[m][n] = (f32x4){0.f, 0.f, 0.f, 0.f};

    for (int k0 = 0; k0 < IN_F; k0 += 32) {
        float4 v0 = *(const float4*)(xrow + k0 + ah);
        float4 v1 = *(const float4*)(xrow + k0 + ah + 4);
        float4 v2 = *(const float4*)(xrow + k0 + ah + 8);
        float4 v3 = *(const float4*)(xrow + k0 + ah + 12);
        short8 p0, p1;
        p0[0] = f2bf(v0.x); p0[1] = f2bf(v0.y); p0[2] = f2bf(v0.z); p0[3] = f2bf(v0.w);
        p0[4] = f2bf(v1.x); p0[5] = f2bf(v1.y); p0[6] = f2bf(v1.z); p0[7] = f2bf(v1.w);
        p1[0] = f2bf(v2.x); p1[1] = f2bf(v2.y); p1[2] = f2bf(v2.z); p1[3] = f2bf(v2.w);
        p1[4] = f2bf(v3.x); p1[5] = f2bf(v3.y); p1[6] = f2bf(v3.z); p1[7] = f2bf(v3.w);
        short8 q0 = *(const short8*)(wrow + k0 + ah);
        short8 q1 = *(const short8*)(wrow + k0 + ah + 8);
        __syncthreads();
        *(short8*)&As[arow * AB_PITCH + ah] = p0;
        *(short8*)&As[arow * AB_PITCH + ah + 8] = p1;
        *(short8*)&Bs[arow * AB_PITCH + ah] = q0;
        *(short8*)&Bs[arow * AB_PITCH + ah + 8] = q1;
        __syncthreads();
        short8 af0 = *(const short8*)&As[(32 * w + l15) * AB_PITCH + koff];
        short8 af1 = *(const short8*)&As[(32 * w + 16 + l15) * AB_PITCH + koff];
        #pragma unroll
        for (int n = 0; n < 8; ++n) {
            short8 bf = *(const short8*)&Bs[(16 * n + l15) * AB_PITCH + koff];
            acc[0][n] = __builtin_amdgcn_mfma_f32_16x16x32_bf16(af0, bf, acc[0][n], 0, 0, 0);
            acc[1][n] = __builtin_amdgcn_mfma_f32_16x16x32_bf16(af1, bf, acc[1][n], 0, 0, 0);
        }
    }

    float bcol[8];
    #pragma unroll
    for (int n = 0; n < 8; ++n) bcol[n] = b1[16 * n + l15];
    __syncthreads();
    #pragma unroll
    for (int m = 0; m < 2; ++m)
        #pragma unroll
        for (int n = 0; n < 8; ++n)
            #pragma unroll
            for (int reg = 0; reg < 4; ++reg) {
                int hrow = 32 * w + 16 * m + ((l >> 4) << 2) + reg;
                float v = fmaxf(acc[m][n][reg] + bcol[n], 0.f);
                H1s[hrow * H1_PITCH + 16 * n + l15] = (short)f2bf(v);
            }
    __syncthreads();

    f32x4 acc2[2][2];
    #pragma unroll
    for (int m = 0; m < 2; ++m)
        #pragma unroll
        for (int n = 0; n < 2; ++n) acc2[m][n] = (f32x4){0.f, 0.f, 0.f, 0.f};
    #pragma unroll
    for (int kc = 0; kc < 4; ++kc) {
        short8 a0 = *(const short8*)&H1s[(32 * w + l15) * H1_PITCH + (kc << 5) + koff];
        short8 a1 = *(const short8*)&H1s[(32 * w + 16 + l15) * H1_PITCH + (kc << 5) + koff];
        #pragma unroll
        for (int n = 0; n < 2; ++n) {
            short8 bf = *(const short8*)&W2s[(16 * n + l15) * H1_PITCH + (kc << 5) + koff];
            acc2[0][n] = __builtin_amdgcn_mfma_f32_16x16x32_bf16(a0, bf, acc2[0][n], 0, 0, 0);
            acc2[1][n] = __builtin_amdgcn_mfma_f32_16x16x32_bf16(a1, bf, acc2[1][n], 0, 0, 0);
        }
    }
    #pragma unroll
    for (int n = 0; n < 2; ++n) {
        float bc = b2[16 * n + l15];
        #pragma unroll
        for (int m = 0; m < 2; ++m)
            #pragma unroll
            for (int reg = 0; reg < 4; ++reg) {
                int row = 32 * w + 16 * m + ((l >> 4) << 2) + reg;
                int g = m0 + row;
                if (g < M)
                    H[(size_t)g * OUT_F + 16 * n + l15] = (_Float16)fmaxf(acc2[m][n][reg] + bc, 0.f);
            }
    }
}

// ============================ SpMM step (fp16 rows, 4 lanes/row) ============================

template <int LAST>
__launch_bounds__(256)
__global__ void spmm_kernel(const int* __restrict__ rowptr, const int2* __restrict__ edges,
                            const half8* __restrict__ src, half8* __restrict__ dst,
                            float* __restrict__ dstf, int n) {
    int g = blockIdx.x * 256 + threadIdx.x;
    int r = g >> 2, lane = g & 3;
    if (r >= n) return;
    int s = rowptr[r], e = rowptr[r + 1];
    float a0 = 0.f, a1 = 0.f, a2 = 0.f, a3 = 0.f, a4 = 0.f, a5 = 0.f, a6 = 0.f, a7 = 0.f;
    int i = s;
    for (; i + 4 <= e; i += 4) {
        int2 e0 = edges[i], e1 = edges[i + 1], e2 = edges[i + 2], e3 = edges[i + 3];
        half8 v0 = src[(size_t)e0.x * 4 + lane];
        half8 v1 = src[(size_t)e1.x * 4 + lane];
        half8 v2 = src[(size_t)e2.x * 4 + lane];
        half8 v3 = src[(size_t)e3.x * 4 + lane];
        float w0 = __int_as_float(e0.y), w1 = __int_as_float(e1.y);
        float w2 = __int_as_float(e2.y), w3 = __int_as_float(e3.y);
        a0 = fmaf(w0, (float)v0[0], a0); a1 = fmaf(w0, (float)v0[1], a1);
        a2 = fmaf(w0, (float)v0[2], a2); a3 = fmaf(w0, (float)v0[3], a3);
        a4 = fmaf(w0, (float)v0[4], a4); a5 = fmaf(w0, (float)v0[5], a5);
        a6 = fmaf(w0, (float)v0[6], a6); a7 = fmaf(w0, (float)v0[7], a7);
        a0 = fmaf(w1, (float)v1[0], a0); a1 = fmaf(w1, (float)v1[1], a1);
        a2 = fmaf(w1, (float)v1[2], a2); a3 = fmaf(w1, (float)v1[3], a3);
        a4 = fmaf(w1, (float)v1[4], a4); a5 = fmaf(w1, (float)v1[5], a5);
        a6 = fmaf(w1, (float)v1[6], a6); a7 = fmaf(w1, (float)v1[7], a7);
        a0 = fmaf(w2, (float)v2[0], a0); a1 = fmaf(w2, (float)v2[1], a1);
        a2 = fmaf(w2, (float)v2[2], a2); a3 = fmaf(w2, (float)v2[3], a3);
        a4 = fmaf(w2, (float)v2[4], a4); a5 = fmaf(w2, (float)v2[5], a5);
        a6 = fmaf(w2, (float)v2[6], a6); a7 = fmaf(w2, (float)v2[7], a7);
        a0 = fmaf(w3, (float)v3[0], a0); a1 = fmaf(w3, (float)v3[1], a1);
        a2 = fmaf(w3, (float)v3[2], a2); a3 = fmaf(w3, (float)v3[3], a3);
        a4 = fmaf(w3, (float)v3[4], a4); a5 = fmaf(w3, (float)v3[5], a5);
        a6 = fmaf(w3, (float)v3[6], a6); a7 = fmaf(w3, (float)v3[7], a7);
    }
    for (; i < e; ++i) {
        int2 e0 = edges[i];
        half8 v0 = src[(size_t)e0.x * 4 + lane];
        float w0 = __int_as_float(e0.y);
        a0 = fmaf(w0, (float)v0[0], a0); a1 = fmaf(w0, (float)v0[1], a1);
        a2 = fmaf(w0, (float)v0[2], a2); a3 = fmaf(w0, (float)v0[3], a3);
        a4 = fmaf(w0, (float)v0[4], a4); a5 = fmaf(w0, (float)v0[5], a5);
        a6 = fmaf(w0, (float)v0[6], a6); a7 = fmaf(w0, (float)v0[7], a7);
    }
    half8 self = src[(size_t)r * 4 + lane];
    float r0 = (1.f - ALPHA) * a0 + ALPHA * (float)self[0];
    float r1 = (1.f - ALPHA) * a1 + ALPHA * (float)self[1];
    float r2 = (1.f - ALPHA) * a2 + ALPHA * (float)self[2];
    float r3 = (1.f - ALPHA) * a3 + ALPHA * (float)self[3];
    float r4 = (1.f - ALPHA) * a4 + ALPHA * (float)self[4];
    float r5 = (1.f - ALPHA) * a5 + ALPHA * (float)self[5];
    float r6 = (1.f - ALPHA) * a6 + ALPHA * (float)self[6];
    float r7 = (1.f - ALPHA) * a7 + ALPHA * (float)self[7];
    if (LAST) {
        float* o = dstf + (size_t)r * OUT_F + lane * 8;
        *(float4*)o = make_float4(r0, r1, r2, r3);
        *(float4*)(o + 4) = make_float4(r4, r5, r6, r7);
    } else {
        half8 o;
        o[0] = (_Float16)r0; o[1] = (_Float16)r1; o[2] = (_Float16)r2; o[3] = (_Float16)r3;
        o[4] = (_Float16)r4; o[5] = (_Float16)r5; o[6] = (_Float16)r6; o[7] = (_Float16)r7;
        dst[(size_t)r * 4 + lane] = o;
    }
}

// ============================ launch ============================

extern "C" void kernel_launch(void* const* d_in, const int* in_sizes, int n_in,
                              void* d_out, int out_size, void* d_ws, size_t ws_size,
                              hipStream_t stream) {
    const float* x  = (const float*)d_in[0];
    const int*   er = (const int*)d_in[1];
    const int*   ec = (const int*)d_in[2];
    const float* ev = (const float*)d_in[3];
    const float* W1 = (const float*)d_in[4];
    const float* b1 = (const float*)d_in[5];
    const float* W2 = (const float*)d_in[6];
    const float* b2 = (const float*)d_in[7];
    float* out = (float*)d_out;

    char* ws = (char*)d_ws;
    _Float16* bufA  = (_Float16*)(ws + 0);         // 6,400,000
    _Float16* bufB  = (_Float16*)(ws + 6400000);   // 6,400,000
    int2*  edges  = (int2*) (ws + 12800000);       // 12,800,000
    int2*  sorted = (int2*) (ws + 25600000);       // 12,800,000
    short* W1T    = (short*)(ws + 38400000);       // 131,072
    short* W2T    = (short*)(ws + 38531072);       // 8,192
    int*   rowptr = (int*)  (ws + 38539264);       // 400,016
    int*   S      = (int*)  (ws + 38939280);       // 400,384
    int*   Spart  = (int*)  (ws + 39339664);       // 400,384
    int*   Sexcl  = (int*)  (ws + 39740048);       // 400,384
    int*   bsum   = (int*)  (ws + 40140432);       // 1,024

    // ---- CSR build (bucketed, no global atomics) ----
    p1_hist_kernel<<<NB, 256, 0, stream>>>(er, S);
    int nb = (NS + SCAN_B - 1) / SCAN_B;  // 196
    scan_block_kernel<<<nb, SCAN_B, 0, stream>>>(S, Spart, bsum, NS);
    scan_tops_kernel<<<1, 256, 0, stream>>>(bsum, nb);
    scan_finish_excl_kernel<<<(NS + 255) / 256, 256, 0, stream>>>(Spart, bsum, S, Sexcl, NS);
    p1_scatter_kernel<<<NB, 256, 0, stream>>>(er, ec, ev, Sexcl, sorted);
    p2_build_kernel<<<NBUCK, 256, 0, stream>>>(sorted, Sexcl, rowptr, edges);

    // ---- weights to bf16 (transposed) ----
    wconv_kernel<<<(IN_F * HID + 255) / 256, 256, 0, stream>>>(W1, W2, W1T, W2T);

    // ---- fused MLP ----
    mlp_kernel<<<(N_NODES + 127) / 128, 256, 0, stream>>>(x, W1T, b1, W2T, b2, bufA, N_NODES);

    // ---- propagation (fp16) ----
    _Float16* src = bufA;
    for (int step = 0; step < K_STEPS; ++step) {
        _Float16* dst = (step & 1) ? bufA : bufB;
        int grid = (N_NODES * 4 + 255) / 256;
        if (step == K_STEPS - 1)
            spmm_kernel<1><<<grid, 256, 0, stream>>>(rowptr, edges, (const half8*)src,
                                                     (half8*)dst, out, N_NODES);
        else
            spmm_kernel<0><<<grid, 256, 0, stream>>>(rowptr, edges, (const half8*)src,
                                                     (half8*)dst, nullptr, N_NODES);
        src = dst;
    }
}